// Round 5
// baseline (865.185 us; speedup 1.0000x reference)
//
#include <hip/hip_runtime.h>
#include <hip/hip_bf16.h>
#include <stdint.h>

#define HID 128
#define BSHIFT 7
#define BCAP 3072   // max edges per 128-node bucket; mean=2048, std~45 -> 22 sigma headroom

typedef __attribute__((ext_vector_type(8))) __bf16 bf16x8;
typedef __attribute__((ext_vector_type(4))) float f32x4;

static __device__ __forceinline__ float bf2f(ushort h){
  union { uint u; float f; } c; c.u = ((uint)h) << 16; return c.f;
}
static __device__ __forceinline__ ushort f2bf(float f){
  union { float f; uint u; } c; c.f = f;
  uint u = c.u;
  return (ushort)((u + 0x7fffu + ((u >> 16) & 1u)) >> 16);
}
static __device__ __forceinline__ bf16x8 load8(const ushort* p){
  return *(const bf16x8*)p;
}

// ---------------- f32 -> bf16 convert (emb) ----------------
__global__ void k_cvt(const float* __restrict__ in, ushort* __restrict__ out, int n){
  int i = blockIdx.x * 256 + threadIdx.x;
  if (i < n) out[i] = f2bf(in[i]);
}

// ---- layer weights f32 -> bf16 frag-major: [layer][kt4][mat2][jt8][lane64][e8] ----
__global__ void k_cvtw(const float* __restrict__ Wl, const float* __restrict__ Wr,
                       ushort* __restrict__ outF, int total){
  int o = blockIdx.x * 256 + threadIdx.x;
  if (o >= total) return;
  int layer = o >> 15;
  int r = o & 32767;
  int e    = r & 7;
  int lane = (r >> 3) & 63;
  int jt   = (r >> 9) & 7;
  int mat  = (r >> 12) & 1;
  int kt   = r >> 13;
  int l16 = lane & 15, quad = lane >> 4;
  int j = jt * 16 + l16;
  int k = kt * 32 + quad * 8 + e;
  const float* W = mat ? Wr : Wl;
  outF[o] = f2bf(W[layer * 16384 + j * 128 + k]);
}

// ---- jk weights f32 -> bf16 frag-major: [kt16][jt8][lane64][e8] ----
__global__ void k_cvtjk(const float* __restrict__ jkW, ushort* __restrict__ outF){
  int o = blockIdx.x * 256 + threadIdx.x;   // total 65536
  int e    = o & 7;
  int lane = (o >> 3) & 63;
  int jt   = (o >> 9) & 7;
  int kt   = o >> 12;
  int l16 = lane & 15, quad = lane >> 4;
  int j = jt * 16 + l16;
  int k = kt * 32 + quad * 8 + e;
  outF[o] = f2bf(jkW[j * 512 + k]);
}

// ---------------- binned CSR build ----------------
// Pass A: coarse-bin edges by dst>>7; packed payload = (src<<7) | (dst & 127).
__global__ void k_bin(const int* __restrict__ src, const int* __restrict__ dst,
                      int* __restrict__ bcnt, uint* __restrict__ binned, int E){
  int e = blockIdx.x * 256 + threadIdx.x;
  if (e < E){
    int d = dst[e];
    int b = d >> BSHIFT;
    int pos = atomicAdd(&bcnt[b], 1);
    if (pos < BCAP)
      binned[(size_t)b * BCAP + pos] = ((uint)src[e] << BSHIFT) | (uint)(d & 127);
  }
}

// Exclusive scan of (clamped) bucket counts -> bucket bases. One block, NB <= 1024.
__global__ void k_bscan(const int* __restrict__ bcnt, int* __restrict__ bbase, int nb){
  int tid = threadIdx.x;
  int v = (tid < nb) ? min(bcnt[tid], BCAP) : 0;
  int lane = tid & 63, w = tid >> 6;
  int x = v;
  #pragma unroll
  for (int d = 1; d < 64; d <<= 1){ int y = __shfl_up(x, d, 64); if (lane >= d) x += y; }
  __shared__ int tmp[16];
  if (lane == 63) tmp[w] = x;
  __syncthreads();
  if (tid < 64){
    int s = (lane < 16) ? tmp[lane] : 0;
    #pragma unroll
    for (int d = 1; d < 16; d <<= 1){ int y = __shfl_up(s, d, 64); if (lane >= d) s += y; }
    if (lane < 16) tmp[lane] = s;
  }
  __syncthreads();
  int base = (w > 0) ? tmp[w - 1] : 0;
  if (tid < nb) bbase[tid] = base + x - v;   // exclusive
}

// Pass B: one block per bucket. LDS-count 128 local nodes, scan, emit offs/cnt, scatter csr.
__global__ __launch_bounds__(256) void k_bpass(
    const uint* __restrict__ binned, const int* __restrict__ bcnt,
    const int* __restrict__ bbase, int* __restrict__ csr,
    int* __restrict__ offs, int* __restrict__ cnt, int N){
  int b = blockIdx.x;
  int n0 = b << BSHIFT;
  int tid = threadIdx.x;
  __shared__ int lcnt[128], loffs[128];
  if (tid < 128) lcnt[tid] = 0;
  __syncthreads();
  int m = min(bcnt[b], BCAP);
  const uint* bp = binned + (size_t)b * BCAP;
  uint vv[12]; int slot[12];
  #pragma unroll
  for (int u = 0; u < 12; u++){
    int i = tid + u * 256;
    if (i < m){
      uint v = bp[i];
      vv[u] = v;
      slot[u] = atomicAdd(&lcnt[v & 127], 1);
    }
  }
  __syncthreads();
  if (tid < 64){
    int a0 = lcnt[tid * 2], a1 = lcnt[tid * 2 + 1];
    int s = a0 + a1;
    int x = s;
    #pragma unroll
    for (int d = 1; d < 64; d <<= 1){ int y = __shfl_up(x, d, 64); if (tid >= d) x += y; }
    int excl = x - s;
    loffs[tid * 2] = excl;
    loffs[tid * 2 + 1] = excl + a0;
  }
  __syncthreads();
  int base = bbase[b];
  if (tid < 128 && n0 + tid < N){
    cnt[n0 + tid] = lcnt[tid];
    offs[n0 + tid] = base + loffs[tid];
  }
  #pragma unroll
  for (int u = 0; u < 12; u++){
    int i = tid + u * 256;
    if (i < m){
      uint v = vv[u];
      csr[base + loffs[v & 127] + slot[u]] = (int)(v >> BSHIFT);
    }
  }
}

// ---------------- scatter-mean aggregation (wave per node, unroll-8) ----------------
__global__ __launch_bounds__(256) void k_aggregate(
    const ushort* __restrict__ x, const int* __restrict__ csr,
    const int* __restrict__ offs, const int* __restrict__ cnt,
    ushort* __restrict__ agg, int N){
  int node = blockIdx.x * 4 + (threadIdx.x >> 6);
  int lane = threadIdx.x & 63;
  if (node >= N) return;
  int beg = offs[node], d = cnt[node];
  const int* __restrict__ cp = csr + beg;
  float s0 = 0.f, s1 = 0.f;
  int i = 0;
  for (; i + 8 <= d; i += 8){
    int idx[8];
    #pragma unroll
    for (int u = 0; u < 8; u++) idx[u] = cp[i + u];
    uint v[8];
    #pragma unroll
    for (int u = 0; u < 8; u++)
      v[u] = *(const uint*)(x + (size_t)idx[u] * HID + lane * 2);
    #pragma unroll
    for (int u = 0; u < 8; u++){
      s0 += bf2f((ushort)v[u]);
      s1 += bf2f((ushort)(v[u] >> 16));
    }
  }
  if (i + 4 <= d){
    int idx[4];
    #pragma unroll
    for (int u = 0; u < 4; u++) idx[u] = cp[i + u];
    uint v[4];
    #pragma unroll
    for (int u = 0; u < 4; u++)
      v[u] = *(const uint*)(x + (size_t)idx[u] * HID + lane * 2);
    #pragma unroll
    for (int u = 0; u < 4; u++){
      s0 += bf2f((ushort)v[u]);
      s1 += bf2f((ushort)(v[u] >> 16));
    }
    i += 4;
  }
  for (; i < d; i++){
    int s = cp[i];
    uint v = *(const uint*)(x + (size_t)s * HID + lane * 2);
    s0 += bf2f((ushort)v);
    s1 += bf2f((ushort)(v >> 16));
  }
  float inv = 1.0f / fmaxf((float)d, 1.0f);
  uint o = (uint)f2bf(s0 * inv) | ((uint)f2bf(s1 * inv) << 16);
  *(uint*)(agg + (size_t)node * HID + lane * 2) = o;
}

// ---------------- fused dual-GEMM + bias + LN + ReLU + residual ----------------
// 128 rows/block (4 waves x 2 rowtiles). B staged via LDS in frag-major order.
template<int HAS_RES>
__global__ __launch_bounds__(256) void k_layer(
    const ushort* __restrict__ agg, const ushort* __restrict__ xin,
    const ushort* __restrict__ Wf,     // [kt4][mat2][jt8][lane64][8] bf16
    const float* __restrict__ bl, const float* __restrict__ gamma,
    const float* __restrict__ beta,
    ushort* __restrict__ xout, int N){
  __shared__ ushort sB[8192];
  int tid = threadIdx.x;
  int wv = tid >> 6, lane = tid & 63;
  int quad = lane >> 4, l16 = lane & 15;
  int rowbase = blockIdx.x * 128 + wv * 32;
  int r0 = rowbase + l16;      if (r0 >= N) r0 = N - 1;
  int r1 = rowbase + 16 + l16; if (r1 >= N) r1 = N - 1;

  f32x4 acc[2][8];
  #pragma unroll
  for (int jt = 0; jt < 8; jt++){
    float b = bl[jt * 16 + l16];
    f32x4 c = {b, b, b, b};
    acc[0][jt] = c; acc[1][jt] = c;
  }

  #pragma unroll
  for (int kt = 0; kt < 4; kt++){
    int ao = kt * 32 + quad * 8;
    bf16x8 a10 = load8(agg + (size_t)r0 * HID + ao);
    bf16x8 a11 = load8(agg + (size_t)r1 * HID + ao);
    bf16x8 a20 = load8(xin + (size_t)r0 * HID + ao);
    bf16x8 a21 = load8(xin + (size_t)r1 * HID + ao);
    __syncthreads();
    const ushort* src = Wf + kt * 8192;
    #pragma unroll
    for (int i = 0; i < 4; i++){
      int c = i * 256 + tid;
      *(bf16x8*)(sB + c * 8) = load8(src + c * 8);
    }
    __syncthreads();
    #pragma unroll
    for (int jt = 0; jt < 8; jt++){
      bf16x8 bL = load8(sB + (jt * 64 + lane) * 8);
      bf16x8 bR = load8(sB + ((8 + jt) * 64 + lane) * 8);
      acc[0][jt] = __builtin_amdgcn_mfma_f32_16x16x32_bf16(a10, bL, acc[0][jt], 0, 0, 0);
      acc[1][jt] = __builtin_amdgcn_mfma_f32_16x16x32_bf16(a11, bL, acc[1][jt], 0, 0, 0);
      acc[0][jt] = __builtin_amdgcn_mfma_f32_16x16x32_bf16(a20, bR, acc[0][jt], 0, 0, 0);
      acc[1][jt] = __builtin_amdgcn_mfma_f32_16x16x32_bf16(a21, bR, acc[1][jt], 0, 0, 0);
    }
  }

  #pragma unroll
  for (int rt = 0; rt < 2; rt++){
    float s1[4] = {0,0,0,0}, s2[4] = {0,0,0,0};
    #pragma unroll
    for (int jt = 0; jt < 8; jt++){
      #pragma unroll
      for (int r = 0; r < 4; r++){ float v = acc[rt][jt][r]; s1[r] += v; s2[r] += v * v; }
    }
    #pragma unroll
    for (int m = 1; m < 16; m <<= 1){
      #pragma unroll
      for (int r = 0; r < 4; r++){
        s1[r] += __shfl_xor(s1[r], m, 64);
        s2[r] += __shfl_xor(s2[r], m, 64);
      }
    }
    float mu[4], rs[4];
    #pragma unroll
    for (int r = 0; r < 4; r++){
      mu[r] = s1[r] * (1.f / 128.f);
      float var = s2[r] * (1.f / 128.f) - mu[r] * mu[r];
      rs[r] = rsqrtf(var + 1e-5f);
    }
    #pragma unroll
    for (int jt = 0; jt < 8; jt++){
      int col = jt * 16 + l16;
      float g = gamma[col], bb = beta[col];
      #pragma unroll
      for (int r = 0; r < 4; r++){
        int row = rowbase + rt * 16 + quad * 4 + r;
        if (row < N){
          float v = (acc[rt][jt][r] - mu[r]) * rs[r] * g + bb;
          v = fmaxf(v, 0.f);
          if (HAS_RES) v += bf2f(xin[(size_t)row * HID + col]);
          xout[(size_t)row * HID + col] = f2bf(v);
        }
      }
    }
  }
}

// ---------------- JK: out = [emb,x1,x2,x3] @ jkW^T + jkb  (out f32) ----------------
__global__ __launch_bounds__(256) void k_jk(
    const ushort* __restrict__ emb, const ushort* __restrict__ x1,
    const ushort* __restrict__ x2, const ushort* __restrict__ x3,
    const ushort* __restrict__ Wf,   // [kt16][jt8][lane64][8] bf16
    const float* __restrict__ jkb, float* __restrict__ out, int N){
  __shared__ ushort sB[8192];
  int tid = threadIdx.x;
  int wv = tid >> 6, lane = tid & 63;
  int quad = lane >> 4, l16 = lane & 15;
  int rowbase = blockIdx.x * 128 + wv * 32;
  int r0 = rowbase + l16;      if (r0 >= N) r0 = N - 1;
  int r1 = rowbase + 16 + l16; if (r1 >= N) r1 = N - 1;

  f32x4 acc[2][8];
  #pragma unroll
  for (int jt = 0; jt < 8; jt++){
    float b = jkb[jt * 16 + l16];
    f32x4 c = {b, b, b, b};
    acc[0][jt] = c; acc[1][jt] = c;
  }

  const ushort* srcs[4] = {emb, x1, x2, x3};
  #pragma unroll
  for (int st = 0; st < 8; st++){
    int kt0 = st * 2, kt1 = st * 2 + 1;
    const ushort* sp0 = srcs[kt0 >> 2];
    const ushort* sp1 = srcs[kt1 >> 2];
    int ao0 = (kt0 & 3) * 32 + quad * 8;
    int ao1 = (kt1 & 3) * 32 + quad * 8;
    bf16x8 aA0 = load8(sp0 + (size_t)r0 * HID + ao0);
    bf16x8 aA1 = load8(sp0 + (size_t)r1 * HID + ao0);
    bf16x8 aB0 = load8(sp1 + (size_t)r0 * HID + ao1);
    bf16x8 aB1 = load8(sp1 + (size_t)r1 * HID + ao1);
    __syncthreads();
    const ushort* src = Wf + st * 8192;
    #pragma unroll
    for (int i = 0; i < 4; i++){
      int c = i * 256 + tid;
      *(bf16x8*)(sB + c * 8) = load8(src + c * 8);
    }
    __syncthreads();
    #pragma unroll
    for (int jt = 0; jt < 8; jt++){
      bf16x8 b0 = load8(sB + (jt * 64 + lane) * 8);
      bf16x8 b1 = load8(sB + ((8 + jt) * 64 + lane) * 8);
      acc[0][jt] = __builtin_amdgcn_mfma_f32_16x16x32_bf16(aA0, b0, acc[0][jt], 0, 0, 0);
      acc[1][jt] = __builtin_amdgcn_mfma_f32_16x16x32_bf16(aA1, b0, acc[1][jt], 0, 0, 0);
      acc[0][jt] = __builtin_amdgcn_mfma_f32_16x16x32_bf16(aB0, b1, acc[0][jt], 0, 0, 0);
      acc[1][jt] = __builtin_amdgcn_mfma_f32_16x16x32_bf16(aB1, b1, acc[1][jt], 0, 0, 0);
    }
  }

  #pragma unroll
  for (int rt = 0; rt < 2; rt++){
    #pragma unroll
    for (int jt = 0; jt < 8; jt++){
      #pragma unroll
      for (int r = 0; r < 4; r++){
        int row = rowbase + rt * 16 + quad * 4 + r;
        if (row < N)
          out[(size_t)row * HID + jt * 16 + l16] = acc[rt][jt][r];
      }
    }
  }
}

extern "C" void kernel_launch(void* const* d_in, const int* in_sizes, int n_in,
                              void* d_out, int out_size, void* d_ws, size_t ws_size,
                              hipStream_t stream){
  const float* emb   = (const float*)d_in[0];
  const float* Wl    = (const float*)d_in[1];
  const float* bl    = (const float*)d_in[2];
  const float* Wr    = (const float*)d_in[3];
  const float* gamma = (const float*)d_in[4];
  const float* beta  = (const float*)d_in[5];
  const float* jkW   = (const float*)d_in[6];
  const float* jkb   = (const float*)d_in[7];
  const int*   eidx  = (const int*)d_in[8];
  int N = in_sizes[0] / HID;
  int E = in_sizes[8] / 2;
  const int* src = eidx;
  const int* dst = eidx + E;
  float* out = (float*)d_out;

  int NB = (N + 127) >> BSHIFT;   // coarse buckets of 128 nodes

  // workspace carve (256B aligned)
  char* w = (char*)d_ws;
  auto carve = [&](size_t bytes) -> char* {
    char* p = w; w += (bytes + 255) & ~(size_t)255; return p;
  };
  int Npad = ((N + 127) / 128) * 128;
  int* bcnt     = (int*)carve((size_t)NB * 4);
  int* bbase    = (int*)carve((size_t)NB * 4);
  uint* binned  = (uint*)carve((size_t)NB * BCAP * 4);
  int* cnt      = (int*)carve((size_t)N * 4);
  int* offs     = (int*)carve((size_t)N * 4);
  int* csr      = (int*)carve((size_t)E * 4);
  ushort* Wfrag = (ushort*)carve((size_t)3 * 32768 * 2);
  ushort* jkWf  = (ushort*)carve((size_t)65536 * 2);
  ushort* embbf = (ushort*)carve((size_t)Npad * HID * 2);
  ushort* agg   = (ushort*)carve((size_t)Npad * HID * 2);
  ushort* x1    = (ushort*)carve((size_t)Npad * HID * 2);
  ushort* x2    = (ushort*)carve((size_t)Npad * HID * 2);
  ushort* x3    = (ushort*)carve((size_t)Npad * HID * 2);

  hipMemsetAsync(bcnt, 0, (size_t)NB * 4, stream);

  // weight transforms + emb cast
  int nEmb = N * HID;
  k_cvtw<<<(3 * 32768 + 255) / 256, 256, 0, stream>>>(Wl, Wr, Wfrag, 3 * 32768);
  k_cvtjk<<<65536 / 256, 256, 0, stream>>>(jkW, jkWf);
  k_cvt<<<(nEmb + 255) / 256, 256, 0, stream>>>(emb, embbf, nEmb);

  // binned CSR build
  k_bin<<<(E + 255) / 256, 256, 0, stream>>>(src, dst, bcnt, binned, E);
  k_bscan<<<1, 1024, 0, stream>>>(bcnt, bbase, NB);
  k_bpass<<<NB, 256, 0, stream>>>(binned, bcnt, bbase, csr, offs, cnt, N);

  int aggBlocks = (N + 3) / 4;
  int gemmBlocks = (N + 127) / 128;

  // layer 0 (no residual)
  k_aggregate<<<aggBlocks, 256, 0, stream>>>(embbf, csr, offs, cnt, agg, N);
  k_layer<0><<<gemmBlocks, 256, 0, stream>>>(agg, embbf, Wfrag, bl, gamma, beta, x1, N);
  // layer 1
  k_aggregate<<<aggBlocks, 256, 0, stream>>>(x1, csr, offs, cnt, agg, N);
  k_layer<1><<<gemmBlocks, 256, 0, stream>>>(agg, x1, Wfrag + 32768, bl + HID,
                                             gamma + HID, beta + HID, x2, N);
  // layer 2
  k_aggregate<<<aggBlocks, 256, 0, stream>>>(x2, csr, offs, cnt, agg, N);
  k_layer<1><<<gemmBlocks, 256, 0, stream>>>(agg, x2, Wfrag + 2 * 32768, bl + 2 * HID,
                                             gamma + 2 * HID, beta + 2 * HID, x3, N);
  // jumping knowledge projection
  k_jk<<<gemmBlocks, 256, 0, stream>>>(embbf, x1, x2, x3, jkWf, jkb, out, N);
}

// Round 6
// 563.789 us; speedup vs baseline: 1.5346x; 1.5346x over previous
//
#include <hip/hip_runtime.h>
#include <hip/hip_bf16.h>
#include <stdint.h>

#define HID 128
#define BSHIFT 7
#define NBLK 64      // edge-slice blocks for count/place

typedef __attribute__((ext_vector_type(8))) __bf16 bf16x8;
typedef __attribute__((ext_vector_type(4))) float f32x4;

static __device__ __forceinline__ float bf2f(ushort h){
  union { uint u; float f; } c; c.u = ((uint)h) << 16; return c.f;
}
static __device__ __forceinline__ ushort f2bf(float f){
  union { float f; uint u; } c; c.f = f;
  uint u = c.u;
  return (ushort)((u + 0x7fffu + ((u >> 16) & 1u)) >> 16);
}
static __device__ __forceinline__ bf16x8 load8(const ushort* p){
  return *(const bf16x8*)p;
}

// ---------------- f32 -> bf16 convert (emb) ----------------
__global__ void k_cvt(const float* __restrict__ in, ushort* __restrict__ out, int n){
  int i = blockIdx.x * 256 + threadIdx.x;
  if (i < n) out[i] = f2bf(in[i]);
}

// ---- layer weights f32 -> bf16 frag-major: [layer][kt4][mat2][jt8][lane64][e8] ----
__global__ void k_cvtw(const float* __restrict__ Wl, const float* __restrict__ Wr,
                       ushort* __restrict__ outF, int total){
  int o = blockIdx.x * 256 + threadIdx.x;
  if (o >= total) return;
  int layer = o >> 15;
  int r = o & 32767;
  int e    = r & 7;
  int lane = (r >> 3) & 63;
  int jt   = (r >> 9) & 7;
  int mat  = (r >> 12) & 1;
  int kt   = r >> 13;
  int l16 = lane & 15, quad = lane >> 4;
  int j = jt * 16 + l16;
  int k = kt * 32 + quad * 8 + e;
  const float* W = mat ? Wr : Wl;
  outF[o] = f2bf(W[layer * 16384 + j * 128 + k]);
}

// ---- jk weights f32 -> bf16 frag-major: [kt16][jt8][lane64][e8] ----
__global__ void k_cvtjk(const float* __restrict__ jkW, ushort* __restrict__ outF){
  int o = blockIdx.x * 256 + threadIdx.x;   // total 65536
  int e    = o & 7;
  int lane = (o >> 3) & 63;
  int jt   = (o >> 9) & 7;
  int kt   = o >> 12;
  int l16 = lane & 15, quad = lane >> 4;
  int j = jt * 16 + l16;
  int k = kt * 32 + quad * 8 + e;
  outF[o] = f2bf(jkW[j * 512 + k]);
}

// ================ deterministic two-level CSR build (no global atomics) ================
// Pass 1: per-block LDS histogram of coarse buckets (dst>>7) -> rowcnt[blk][b]
__global__ __launch_bounds__(1024) void k_count(
    const int* __restrict__ dst, int* __restrict__ rowcnt, int E, int NB, int es){
  __shared__ int h[1024];
  int blk = blockIdx.x;
  for (int i = threadIdx.x; i < NB; i += 1024) h[i] = 0;
  __syncthreads();
  int e0 = blk * es, e1 = min(e0 + es, E);
  for (int e = e0 + threadIdx.x; e < e1; e += 1024)
    atomicAdd(&h[dst[e] >> BSHIFT], 1);
  __syncthreads();
  for (int i = threadIdx.x; i < NB; i += 1024)
    rowcnt[blk * NB + i] = h[i];
}

// Pass 2 (1 block): column-scan rowcnt -> absolute starts; bucket totals -> bbase (packed).
__global__ __launch_bounds__(1024) void k_colscan(
    int* __restrict__ rowcnt, int* __restrict__ bbase, int NB, int nblk){
  int b = threadIdx.x;
  int total = 0;
  if (b < NB)
    for (int r = 0; r < nblk; r++) total += rowcnt[r * NB + b];
  // block-wide exclusive scan of totals
  int lane = b & 63, w = b >> 6;
  int x = total;
  #pragma unroll
  for (int d = 1; d < 64; d <<= 1){ int y = __shfl_up(x, d, 64); if (lane >= d) x += y; }
  __shared__ int tmp[16];
  if (lane == 63) tmp[w] = x;
  __syncthreads();
  if (b < 64){
    int s = (lane < 16) ? tmp[lane] : 0;
    #pragma unroll
    for (int d = 1; d < 16; d <<= 1){ int y = __shfl_up(s, d, 64); if (lane >= d) s += y; }
    if (lane < 16) tmp[lane] = s;
  }
  __syncthreads();
  int base = ((w > 0) ? tmp[w - 1] : 0) + x - total;  // exclusive
  if (b < NB){
    bbase[b] = base;
    int acc = base;
    for (int r = 0; r < nblk; r++){
      int v = rowcnt[r * NB + b];
      rowcnt[r * NB + b] = acc;
      acc += v;
    }
    if (b == NB - 1) bbase[NB] = acc;
  }
}

// Pass 3: scatter packed payloads into packed bucket regions (LDS cursors, clustered writes).
__global__ __launch_bounds__(1024) void k_place(
    const int* __restrict__ src, const int* __restrict__ dst,
    const int* __restrict__ rowcnt, uint* __restrict__ binned, int E, int NB, int es){
  __shared__ int cur[1024];
  int blk = blockIdx.x;
  for (int i = threadIdx.x; i < NB; i += 1024) cur[i] = rowcnt[blk * NB + i];
  __syncthreads();
  int e0 = blk * es, e1 = min(e0 + es, E);
  for (int e = e0 + threadIdx.x; e < e1; e += 1024){
    int d = dst[e];
    int b = d >> BSHIFT;
    int pos = atomicAdd(&cur[b], 1);
    binned[pos] = ((uint)src[e] << BSHIFT) | (uint)(d & 127);
  }
}

// Pass 4: one block per bucket. LDS-count 128 local nodes, scan, emit offs/cnt, scatter csr.
__global__ __launch_bounds__(256) void k_bpass(
    const uint* __restrict__ binned, const int* __restrict__ bbase,
    int* __restrict__ csr, int* __restrict__ offs, int* __restrict__ cnt, int N){
  int b = blockIdx.x;
  int n0 = b << BSHIFT;
  int tid = threadIdx.x;
  __shared__ int lcnt[128], loffs[128];
  if (tid < 128) lcnt[tid] = 0;
  __syncthreads();
  int base = bbase[b];
  int m = bbase[b + 1] - base;
  const uint* bp = binned + base;
  uint vv[12]; int slot[12];
  #pragma unroll
  for (int u = 0; u < 12; u++){
    int i = tid + u * 256;
    if (i < m){
      uint v = bp[i];
      vv[u] = v;
      slot[u] = atomicAdd(&lcnt[v & 127], 1);
    }
  }
  __syncthreads();
  if (tid < 64){
    int a0 = lcnt[tid * 2], a1 = lcnt[tid * 2 + 1];
    int s = a0 + a1;
    int x = s;
    #pragma unroll
    for (int d = 1; d < 64; d <<= 1){ int y = __shfl_up(x, d, 64); if (tid >= d) x += y; }
    int excl = x - s;
    loffs[tid * 2] = excl;
    loffs[tid * 2 + 1] = excl + a0;
  }
  __syncthreads();
  if (tid < 128 && n0 + tid < N){
    cnt[n0 + tid] = lcnt[tid];
    offs[n0 + tid] = base + loffs[tid];
  }
  #pragma unroll
  for (int u = 0; u < 12; u++){
    int i = tid + u * 256;
    if (i < m){
      uint v = vv[u];
      csr[base + loffs[v & 127] + slot[u]] = (int)(v >> BSHIFT);
    }
  }
}

// ---------------- scatter-mean aggregation (wave per node, unroll-8) ----------------
__global__ __launch_bounds__(256) void k_aggregate(
    const ushort* __restrict__ x, const int* __restrict__ csr,
    const int* __restrict__ offs, const int* __restrict__ cnt,
    ushort* __restrict__ agg, int N){
  int node = blockIdx.x * 4 + (threadIdx.x >> 6);
  int lane = threadIdx.x & 63;
  if (node >= N) return;
  int beg = offs[node], d = cnt[node];
  const int* __restrict__ cp = csr + beg;
  float s0 = 0.f, s1 = 0.f;
  int i = 0;
  for (; i + 8 <= d; i += 8){
    int idx[8];
    #pragma unroll
    for (int u = 0; u < 8; u++) idx[u] = cp[i + u];
    uint v[8];
    #pragma unroll
    for (int u = 0; u < 8; u++)
      v[u] = *(const uint*)(x + (size_t)idx[u] * HID + lane * 2);
    #pragma unroll
    for (int u = 0; u < 8; u++){
      s0 += bf2f((ushort)v[u]);
      s1 += bf2f((ushort)(v[u] >> 16));
    }
  }
  if (i + 4 <= d){
    int idx[4];
    #pragma unroll
    for (int u = 0; u < 4; u++) idx[u] = cp[i + u];
    uint v[4];
    #pragma unroll
    for (int u = 0; u < 4; u++)
      v[u] = *(const uint*)(x + (size_t)idx[u] * HID + lane * 2);
    #pragma unroll
    for (int u = 0; u < 4; u++){
      s0 += bf2f((ushort)v[u]);
      s1 += bf2f((ushort)(v[u] >> 16));
    }
    i += 4;
  }
  for (; i < d; i++){
    int s = cp[i];
    uint v = *(const uint*)(x + (size_t)s * HID + lane * 2);
    s0 += bf2f((ushort)v);
    s1 += bf2f((ushort)(v >> 16));
  }
  float inv = 1.0f / fmaxf((float)d, 1.0f);
  uint o = (uint)f2bf(s0 * inv) | ((uint)f2bf(s1 * inv) << 16);
  *(uint*)(agg + (size_t)node * HID + lane * 2) = o;
}

// ---------------- fused dual-GEMM + bias + LN + ReLU + residual ----------------
template<int HAS_RES>
__global__ __launch_bounds__(256) void k_layer(
    const ushort* __restrict__ agg, const ushort* __restrict__ xin,
    const ushort* __restrict__ Wf,     // [kt4][mat2][jt8][lane64][8] bf16
    const float* __restrict__ bl, const float* __restrict__ gamma,
    const float* __restrict__ beta,
    ushort* __restrict__ xout, int N){
  __shared__ ushort sB[8192];
  int tid = threadIdx.x;
  int wv = tid >> 6, lane = tid & 63;
  int quad = lane >> 4, l16 = lane & 15;
  int rowbase = blockIdx.x * 128 + wv * 32;
  int r0 = rowbase + l16;      if (r0 >= N) r0 = N - 1;
  int r1 = rowbase + 16 + l16; if (r1 >= N) r1 = N - 1;

  f32x4 acc[2][8];
  #pragma unroll
  for (int jt = 0; jt < 8; jt++){
    float b = bl[jt * 16 + l16];
    f32x4 c = {b, b, b, b};
    acc[0][jt] = c; acc[1][jt] = c;
  }

  #pragma unroll
  for (int kt = 0; kt < 4; kt++){
    int ao = kt * 32 + quad * 8;
    bf16x8 a10 = load8(agg + (size_t)r0 * HID + ao);
    bf16x8 a11 = load8(agg + (size_t)r1 * HID + ao);
    bf16x8 a20 = load8(xin + (size_t)r0 * HID + ao);
    bf16x8 a21 = load8(xin + (size_t)r1 * HID + ao);
    __syncthreads();
    const ushort* src = Wf + kt * 8192;
    #pragma unroll
    for (int i = 0; i < 4; i++){
      int c = i * 256 + tid;
      *(bf16x8*)(sB + c * 8) = load8(src + c * 8);
    }
    __syncthreads();
    #pragma unroll
    for (int jt = 0; jt < 8; jt++){
      bf16x8 bL = load8(sB + (jt * 64 + lane) * 8);
      bf16x8 bR = load8(sB + ((8 + jt) * 64 + lane) * 8);
      acc[0][jt] = __builtin_amdgcn_mfma_f32_16x16x32_bf16(a10, bL, acc[0][jt], 0, 0, 0);
      acc[1][jt] = __builtin_amdgcn_mfma_f32_16x16x32_bf16(a11, bL, acc[1][jt], 0, 0, 0);
      acc[0][jt] = __builtin_amdgcn_mfma_f32_16x16x32_bf16(a20, bR, acc[0][jt], 0, 0, 0);
      acc[1][jt] = __builtin_amdgcn_mfma_f32_16x16x32_bf16(a21, bR, acc[1][jt], 0, 0, 0);
    }
  }

  #pragma unroll
  for (int rt = 0; rt < 2; rt++){
    float s1[4] = {0,0,0,0}, s2[4] = {0,0,0,0};
    #pragma unroll
    for (int jt = 0; jt < 8; jt++){
      #pragma unroll
      for (int r = 0; r < 4; r++){ float v = acc[rt][jt][r]; s1[r] += v; s2[r] += v * v; }
    }
    #pragma unroll
    for (int m = 1; m < 16; m <<= 1){
      #pragma unroll
      for (int r = 0; r < 4; r++){
        s1[r] += __shfl_xor(s1[r], m, 64);
        s2[r] += __shfl_xor(s2[r], m, 64);
      }
    }
    float mu[4], rs[4];
    #pragma unroll
    for (int r = 0; r < 4; r++){
      mu[r] = s1[r] * (1.f / 128.f);
      float var = s2[r] * (1.f / 128.f) - mu[r] * mu[r];
      rs[r] = rsqrtf(var + 1e-5f);
    }
    #pragma unroll
    for (int jt = 0; jt < 8; jt++){
      int col = jt * 16 + l16;
      float g = gamma[col], bb = beta[col];
      #pragma unroll
      for (int r = 0; r < 4; r++){
        int row = rowbase + rt * 16 + quad * 4 + r;
        if (row < N){
          float v = (acc[rt][jt][r] - mu[r]) * rs[r] * g + bb;
          v = fmaxf(v, 0.f);
          if (HAS_RES) v += bf2f(xin[(size_t)row * HID + col]);
          xout[(size_t)row * HID + col] = f2bf(v);
        }
      }
    }
  }
}

// ---------------- JK: out = [emb,x1,x2,x3] @ jkW^T + jkb  (out f32) ----------------
__global__ __launch_bounds__(256) void k_jk(
    const ushort* __restrict__ emb, const ushort* __restrict__ x1,
    const ushort* __restrict__ x2, const ushort* __restrict__ x3,
    const ushort* __restrict__ Wf,   // [kt16][jt8][lane64][8] bf16
    const float* __restrict__ jkb, float* __restrict__ out, int N){
  __shared__ ushort sB[8192];
  int tid = threadIdx.x;
  int wv = tid >> 6, lane = tid & 63;
  int quad = lane >> 4, l16 = lane & 15;
  int rowbase = blockIdx.x * 128 + wv * 32;
  int r0 = rowbase + l16;      if (r0 >= N) r0 = N - 1;
  int r1 = rowbase + 16 + l16; if (r1 >= N) r1 = N - 1;

  f32x4 acc[2][8];
  #pragma unroll
  for (int jt = 0; jt < 8; jt++){
    float b = jkb[jt * 16 + l16];
    f32x4 c = {b, b, b, b};
    acc[0][jt] = c; acc[1][jt] = c;
  }

  const ushort* srcs[4] = {emb, x1, x2, x3};
  #pragma unroll
  for (int st = 0; st < 8; st++){
    int kt0 = st * 2, kt1 = st * 2 + 1;
    const ushort* sp0 = srcs[kt0 >> 2];
    const ushort* sp1 = srcs[kt1 >> 2];
    int ao0 = (kt0 & 3) * 32 + quad * 8;
    int ao1 = (kt1 & 3) * 32 + quad * 8;
    bf16x8 aA0 = load8(sp0 + (size_t)r0 * HID + ao0);
    bf16x8 aA1 = load8(sp0 + (size_t)r1 * HID + ao0);
    bf16x8 aB0 = load8(sp1 + (size_t)r0 * HID + ao1);
    bf16x8 aB1 = load8(sp1 + (size_t)r1 * HID + ao1);
    __syncthreads();
    const ushort* src = Wf + st * 8192;
    #pragma unroll
    for (int i = 0; i < 4; i++){
      int c = i * 256 + tid;
      *(bf16x8*)(sB + c * 8) = load8(src + c * 8);
    }
    __syncthreads();
    #pragma unroll
    for (int jt = 0; jt < 8; jt++){
      bf16x8 b0 = load8(sB + (jt * 64 + lane) * 8);
      bf16x8 b1 = load8(sB + ((8 + jt) * 64 + lane) * 8);
      acc[0][jt] = __builtin_amdgcn_mfma_f32_16x16x32_bf16(aA0, b0, acc[0][jt], 0, 0, 0);
      acc[1][jt] = __builtin_amdgcn_mfma_f32_16x16x32_bf16(aA1, b0, acc[1][jt], 0, 0, 0);
      acc[0][jt] = __builtin_amdgcn_mfma_f32_16x16x32_bf16(aB0, b1, acc[0][jt], 0, 0, 0);
      acc[1][jt] = __builtin_amdgcn_mfma_f32_16x16x32_bf16(aB1, b1, acc[1][jt], 0, 0, 0);
    }
  }

  #pragma unroll
  for (int rt = 0; rt < 2; rt++){
    #pragma unroll
    for (int jt = 0; jt < 8; jt++){
      #pragma unroll
      for (int r = 0; r < 4; r++){
        int row = rowbase + rt * 16 + quad * 4 + r;
        if (row < N)
          out[(size_t)row * HID + jt * 16 + l16] = acc[rt][jt][r];
      }
    }
  }
}

extern "C" void kernel_launch(void* const* d_in, const int* in_sizes, int n_in,
                              void* d_out, int out_size, void* d_ws, size_t ws_size,
                              hipStream_t stream){
  const float* emb   = (const float*)d_in[0];
  const float* Wl    = (const float*)d_in[1];
  const float* bl    = (const float*)d_in[2];
  const float* Wr    = (const float*)d_in[3];
  const float* gamma = (const float*)d_in[4];
  const float* beta  = (const float*)d_in[5];
  const float* jkW   = (const float*)d_in[6];
  const float* jkb   = (const float*)d_in[7];
  const int*   eidx  = (const int*)d_in[8];
  int N = in_sizes[0] / HID;
  int E = in_sizes[8] / 2;
  const int* src = eidx;
  const int* dst = eidx + E;
  float* out = (float*)d_out;

  int NB = (N + 127) >> BSHIFT;        // coarse buckets of 128 nodes (782)
  int es = (E + NBLK - 1) / NBLK;      // edges per slice block

  // workspace carve (256B aligned)
  char* w = (char*)d_ws;
  auto carve = [&](size_t bytes) -> char* {
    char* p = w; w += (bytes + 255) & ~(size_t)255; return p;
  };
  int Npad = ((N + 127) / 128) * 128;
  int* rowcnt   = (int*)carve((size_t)NBLK * NB * 4);
  int* bbase    = (int*)carve((size_t)(NB + 1) * 4);
  uint* binned  = (uint*)carve((size_t)E * 4);
  int* cnt      = (int*)carve((size_t)N * 4);
  int* offs     = (int*)carve((size_t)N * 4);
  int* csr      = (int*)carve((size_t)E * 4);
  ushort* Wfrag = (ushort*)carve((size_t)3 * 32768 * 2);
  ushort* jkWf  = (ushort*)carve((size_t)65536 * 2);
  ushort* embbf = (ushort*)carve((size_t)Npad * HID * 2);
  ushort* agg   = (ushort*)carve((size_t)Npad * HID * 2);
  ushort* x1    = (ushort*)carve((size_t)Npad * HID * 2);
  ushort* x2    = (ushort*)carve((size_t)Npad * HID * 2);
  ushort* x3    = (ushort*)carve((size_t)Npad * HID * 2);

  // weight transforms + emb cast
  int nEmb = N * HID;
  k_cvtw<<<(3 * 32768 + 255) / 256, 256, 0, stream>>>(Wl, Wr, Wfrag, 3 * 32768);
  k_cvtjk<<<65536 / 256, 256, 0, stream>>>(jkW, jkWf);
  k_cvt<<<(nEmb + 255) / 256, 256, 0, stream>>>(emb, embbf, nEmb);

  // deterministic two-level CSR build
  k_count<<<NBLK, 1024, 0, stream>>>(dst, rowcnt, E, NB, es);
  k_colscan<<<1, 1024, 0, stream>>>(rowcnt, bbase, NB, NBLK);
  k_place<<<NBLK, 1024, 0, stream>>>(src, dst, rowcnt, binned, E, NB, es);
  k_bpass<<<NB, 256, 0, stream>>>(binned, bbase, csr, offs, cnt, N);

  int aggBlocks = (N + 3) / 4;
  int gemmBlocks = (N + 127) / 128;

  // layer 0 (no residual)
  k_aggregate<<<aggBlocks, 256, 0, stream>>>(embbf, csr, offs, cnt, agg, N);
  k_layer<0><<<gemmBlocks, 256, 0, stream>>>(agg, embbf, Wfrag, bl, gamma, beta, x1, N);
  // layer 1
  k_aggregate<<<aggBlocks, 256, 0, stream>>>(x1, csr, offs, cnt, agg, N);
  k_layer<1><<<gemmBlocks, 256, 0, stream>>>(agg, x1, Wfrag + 32768, bl + HID,
                                             gamma + HID, beta + HID, x2, N);
  // layer 2
  k_aggregate<<<aggBlocks, 256, 0, stream>>>(x2, csr, offs, cnt, agg, N);
  k_layer<1><<<gemmBlocks, 256, 0, stream>>>(agg, x2, Wfrag + 2 * 32768, bl + 2 * HID,
                                             gamma + 2 * HID, beta + 2 * HID, x3, N);
  // jumping knowledge projection
  k_jk<<<gemmBlocks, 256, 0, stream>>>(embbf, x1, x2, x3, jkWf, jkb, out, N);
}

// Round 7
// 556.366 us; speedup vs baseline: 1.5551x; 1.0133x over previous
//
#include <hip/hip_runtime.h>
#include <hip/hip_bf16.h>
#include <stdint.h>

#define HID 128
#define BSHIFT 7
#define NBLK 64      // edge-slice blocks for count/place

typedef __attribute__((ext_vector_type(8))) __bf16 bf16x8;
typedef __attribute__((ext_vector_type(4))) float f32x4;

static __device__ __forceinline__ float bf2f(ushort h){
  union { uint u; float f; } c; c.u = ((uint)h) << 16; return c.f;
}
static __device__ __forceinline__ ushort f2bf(float f){
  union { float f; uint u; } c; c.f = f;
  uint u = c.u;
  return (ushort)((u + 0x7fffu + ((u >> 16) & 1u)) >> 16);
}
static __device__ __forceinline__ bf16x8 load8(const ushort* p){
  return *(const bf16x8*)p;
}

// ---------------- f32 -> bf16 convert (emb) ----------------
__global__ void k_cvt(const float* __restrict__ in, ushort* __restrict__ out, int n){
  int i = blockIdx.x * 256 + threadIdx.x;
  if (i < n) out[i] = f2bf(in[i]);
}

// ---- layer weights f32 -> bf16 frag-major: [layer][kt4][mat2][jt8][lane64][e8] ----
__global__ void k_cvtw(const float* __restrict__ Wl, const float* __restrict__ Wr,
                       ushort* __restrict__ outF, int total){
  int o = blockIdx.x * 256 + threadIdx.x;
  if (o >= total) return;
  int layer = o >> 15;
  int r = o & 32767;
  int e    = r & 7;
  int lane = (r >> 3) & 63;
  int jt   = (r >> 9) & 7;
  int mat  = (r >> 12) & 1;
  int kt   = r >> 13;
  int l16 = lane & 15, quad = lane >> 4;
  int j = jt * 16 + l16;
  int k = kt * 32 + quad * 8 + e;
  const float* W = mat ? Wr : Wl;
  outF[o] = f2bf(W[layer * 16384 + j * 128 + k]);
}

// ---- jk weights f32 -> bf16 frag-major: [kt16][jt8][lane64][e8] ----
__global__ void k_cvtjk(const float* __restrict__ jkW, ushort* __restrict__ outF){
  int o = blockIdx.x * 256 + threadIdx.x;   // total 65536
  int e    = o & 7;
  int lane = (o >> 3) & 63;
  int jt   = (o >> 9) & 7;
  int kt   = o >> 12;
  int l16 = lane & 15, quad = lane >> 4;
  int j = jt * 16 + l16;
  int k = kt * 32 + quad * 8 + e;
  outF[o] = f2bf(jkW[j * 512 + k]);
}

// ================ deterministic two-level CSR build (no global atomics) ================
__global__ __launch_bounds__(1024) void k_count(
    const int* __restrict__ dst, int* __restrict__ rowcnt, int E, int NB, int es){
  __shared__ int h[1024];
  int blk = blockIdx.x;
  for (int i = threadIdx.x; i < NB; i += 1024) h[i] = 0;
  __syncthreads();
  int e0 = blk * es, e1 = min(e0 + es, E);
  for (int e = e0 + threadIdx.x; e < e1; e += 1024)
    atomicAdd(&h[dst[e] >> BSHIFT], 1);
  __syncthreads();
  for (int i = threadIdx.x; i < NB; i += 1024)
    rowcnt[blk * NB + i] = h[i];
}

__global__ __launch_bounds__(1024) void k_colscan(
    int* __restrict__ rowcnt, int* __restrict__ bbase, int NB, int nblk){
  int b = threadIdx.x;
  int total = 0;
  if (b < NB)
    for (int r = 0; r < nblk; r++) total += rowcnt[r * NB + b];
  int lane = b & 63, w = b >> 6;
  int x = total;
  #pragma unroll
  for (int d = 1; d < 64; d <<= 1){ int y = __shfl_up(x, d, 64); if (lane >= d) x += y; }
  __shared__ int tmp[16];
  if (lane == 63) tmp[w] = x;
  __syncthreads();
  if (b < 64){
    int s = (lane < 16) ? tmp[lane] : 0;
    #pragma unroll
    for (int d = 1; d < 16; d <<= 1){ int y = __shfl_up(s, d, 64); if (lane >= d) s += y; }
    if (lane < 16) tmp[lane] = s;
  }
  __syncthreads();
  int base = ((w > 0) ? tmp[w - 1] : 0) + x - total;  // exclusive
  if (b < NB){
    bbase[b] = base;
    int acc = base;
    for (int r = 0; r < nblk; r++){
      int v = rowcnt[r * NB + b];
      rowcnt[r * NB + b] = acc;
      acc += v;
    }
    if (b == NB - 1) bbase[NB] = acc;
  }
}

__global__ __launch_bounds__(1024) void k_place(
    const int* __restrict__ src, const int* __restrict__ dst,
    const int* __restrict__ rowcnt, uint* __restrict__ binned, int E, int NB, int es){
  __shared__ int cur[1024];
  int blk = blockIdx.x;
  for (int i = threadIdx.x; i < NB; i += 1024) cur[i] = rowcnt[blk * NB + i];
  __syncthreads();
  int e0 = blk * es, e1 = min(e0 + es, E);
  for (int e = e0 + threadIdx.x; e < e1; e += 1024){
    int d = dst[e];
    int b = d >> BSHIFT;
    int pos = atomicAdd(&cur[b], 1);
    binned[pos] = ((uint)src[e] << BSHIFT) | (uint)(d & 127);
  }
}

__global__ __launch_bounds__(256) void k_bpass(
    const uint* __restrict__ binned, const int* __restrict__ bbase,
    int* __restrict__ csr, int* __restrict__ offs, int* __restrict__ cnt, int N){
  int b = blockIdx.x;
  int n0 = b << BSHIFT;
  int tid = threadIdx.x;
  __shared__ int lcnt[128], loffs[128];
  if (tid < 128) lcnt[tid] = 0;
  __syncthreads();
  int base = bbase[b];
  int m = bbase[b + 1] - base;
  const uint* bp = binned + base;
  uint vv[12]; int slot[12];
  #pragma unroll
  for (int u = 0; u < 12; u++){
    int i = tid + u * 256;
    if (i < m){
      uint v = bp[i];
      vv[u] = v;
      slot[u] = atomicAdd(&lcnt[v & 127], 1);
    }
  }
  __syncthreads();
  if (tid < 64){
    int a0 = lcnt[tid * 2], a1 = lcnt[tid * 2 + 1];
    int s = a0 + a1;
    int x = s;
    #pragma unroll
    for (int d = 1; d < 64; d <<= 1){ int y = __shfl_up(x, d, 64); if (tid >= d) x += y; }
    int excl = x - s;
    loffs[tid * 2] = excl;
    loffs[tid * 2 + 1] = excl + a0;
  }
  __syncthreads();
  if (tid < 128 && n0 + tid < N){
    cnt[n0 + tid] = lcnt[tid];
    offs[n0 + tid] = base + loffs[tid];
  }
  #pragma unroll
  for (int u = 0; u < 12; u++){
    int i = tid + u * 256;
    if (i < m){
      uint v = vv[u];
      csr[base + loffs[v & 127] + slot[u]] = (int)(v >> BSHIFT);
    }
  }
}

// ---------------- scatter-mean aggregation v2 ----------------
// Wave per node; lane loads 8B (4 feats); half 0 (lanes 0-31) = even edge,
// half 1 = odd edge. Whole node = ceil(d/16) fully-pipelined masked iterations.
__global__ __launch_bounds__(256) void k_aggregate(
    const ushort* __restrict__ x, const int* __restrict__ csr,
    const int* __restrict__ offs, const int* __restrict__ cnt,
    ushort* __restrict__ agg, int N){
  int node = blockIdx.x * 4 + (threadIdx.x >> 6);
  int lane = threadIdx.x & 63;
  if (node >= N) return;
  int half = lane >> 5;      // which edge of the pair
  int l32  = lane & 31;      // 8B chunk within the row (4 features)
  int beg = offs[node], d = cnt[node];
  if (d == 0){
    if (half == 0){
      uint2 z = {0u, 0u};
      *(uint2*)(agg + (size_t)node * HID + l32 * 4) = z;
    }
    return;
  }
  const int* __restrict__ cp = csr + beg;
  float s0 = 0.f, s1 = 0.f, s2 = 0.f, s3 = 0.f;
  for (int i = 0; i < d; i += 16){
    int idx[8]; float w[8];
    #pragma unroll
    for (int u = 0; u < 8; u++){
      int pos = i + 2 * u + half;
      bool ok = pos < d;
      pos = ok ? pos : d - 1;
      idx[u] = cp[pos];
      w[u] = ok ? 1.f : 0.f;
    }
    uint2 v[8];
    #pragma unroll
    for (int u = 0; u < 8; u++)
      v[u] = *(const uint2*)(x + (size_t)idx[u] * HID + l32 * 4);
    #pragma unroll
    for (int u = 0; u < 8; u++){
      s0 = fmaf(w[u], bf2f((ushort)v[u].x), s0);
      s1 = fmaf(w[u], bf2f((ushort)(v[u].x >> 16)), s1);
      s2 = fmaf(w[u], bf2f((ushort)v[u].y), s2);
      s3 = fmaf(w[u], bf2f((ushort)(v[u].y >> 16)), s3);
    }
  }
  // combine the two halves (each lane then holds the full sum for its 4 feats)
  s0 += __shfl_xor(s0, 32, 64);
  s1 += __shfl_xor(s1, 32, 64);
  s2 += __shfl_xor(s2, 32, 64);
  s3 += __shfl_xor(s3, 32, 64);
  if (half == 0){
    float inv = 1.0f / fmaxf((float)d, 1.0f);
    uint2 o;
    o.x = (uint)f2bf(s0 * inv) | ((uint)f2bf(s1 * inv) << 16);
    o.y = (uint)f2bf(s2 * inv) | ((uint)f2bf(s3 * inv) << 16);
    *(uint2*)(agg + (size_t)node * HID + l32 * 4) = o;
  }
}

// ---------------- fused dual-GEMM + bias + LN + ReLU + residual ----------------
template<int HAS_RES>
__global__ __launch_bounds__(256) void k_layer(
    const ushort* __restrict__ agg, const ushort* __restrict__ xin,
    const ushort* __restrict__ Wf,     // [kt4][mat2][jt8][lane64][8] bf16
    const float* __restrict__ bl, const float* __restrict__ gamma,
    const float* __restrict__ beta,
    ushort* __restrict__ xout, int N){
  __shared__ ushort sB[8192];
  int tid = threadIdx.x;
  int wv = tid >> 6, lane = tid & 63;
  int quad = lane >> 4, l16 = lane & 15;
  int rowbase = blockIdx.x * 128 + wv * 32;
  int r0 = rowbase + l16;      if (r0 >= N) r0 = N - 1;
  int r1 = rowbase + 16 + l16; if (r1 >= N) r1 = N - 1;

  f32x4 acc[2][8];
  #pragma unroll
  for (int jt = 0; jt < 8; jt++){
    float b = bl[jt * 16 + l16];
    f32x4 c = {b, b, b, b};
    acc[0][jt] = c; acc[1][jt] = c;
  }

  #pragma unroll
  for (int kt = 0; kt < 4; kt++){
    int ao = kt * 32 + quad * 8;
    bf16x8 a10 = load8(agg + (size_t)r0 * HID + ao);
    bf16x8 a11 = load8(agg + (size_t)r1 * HID + ao);
    bf16x8 a20 = load8(xin + (size_t)r0 * HID + ao);
    bf16x8 a21 = load8(xin + (size_t)r1 * HID + ao);
    __syncthreads();
    const ushort* src = Wf + kt * 8192;
    #pragma unroll
    for (int i = 0; i < 4; i++){
      int c = i * 256 + tid;
      *(bf16x8*)(sB + c * 8) = load8(src + c * 8);
    }
    __syncthreads();
    #pragma unroll
    for (int jt = 0; jt < 8; jt++){
      bf16x8 bL = load8(sB + (jt * 64 + lane) * 8);
      bf16x8 bR = load8(sB + ((8 + jt) * 64 + lane) * 8);
      acc[0][jt] = __builtin_amdgcn_mfma_f32_16x16x32_bf16(a10, bL, acc[0][jt], 0, 0, 0);
      acc[1][jt] = __builtin_amdgcn_mfma_f32_16x16x32_bf16(a11, bL, acc[1][jt], 0, 0, 0);
      acc[0][jt] = __builtin_amdgcn_mfma_f32_16x16x32_bf16(a20, bR, acc[0][jt], 0, 0, 0);
      acc[1][jt] = __builtin_amdgcn_mfma_f32_16x16x32_bf16(a21, bR, acc[1][jt], 0, 0, 0);
    }
  }

  #pragma unroll
  for (int rt = 0; rt < 2; rt++){
    float s1[4] = {0,0,0,0}, s2[4] = {0,0,0,0};
    #pragma unroll
    for (int jt = 0; jt < 8; jt++){
      #pragma unroll
      for (int r = 0; r < 4; r++){ float v = acc[rt][jt][r]; s1[r] += v; s2[r] += v * v; }
    }
    #pragma unroll
    for (int m = 1; m < 16; m <<= 1){
      #pragma unroll
      for (int r = 0; r < 4; r++){
        s1[r] += __shfl_xor(s1[r], m, 64);
        s2[r] += __shfl_xor(s2[r], m, 64);
      }
    }
    float mu[4], rs[4];
    #pragma unroll
    for (int r = 0; r < 4; r++){
      mu[r] = s1[r] * (1.f / 128.f);
      float var = s2[r] * (1.f / 128.f) - mu[r] * mu[r];
      rs[r] = rsqrtf(var + 1e-5f);
    }
    #pragma unroll
    for (int jt = 0; jt < 8; jt++){
      int col = jt * 16 + l16;
      float g = gamma[col], bb = beta[col];
      #pragma unroll
      for (int r = 0; r < 4; r++){
        int row = rowbase + rt * 16 + quad * 4 + r;
        if (row < N){
          float v = (acc[rt][jt][r] - mu[r]) * rs[r] * g + bb;
          v = fmaxf(v, 0.f);
          if (HAS_RES) v += bf2f(xin[(size_t)row * HID + col]);
          xout[(size_t)row * HID + col] = f2bf(v);
        }
      }
    }
  }
}

// ---------------- JK: out = [emb,x1,x2,x3] @ jkW^T + jkb  (out f32) ----------------
__global__ __launch_bounds__(256) void k_jk(
    const ushort* __restrict__ emb, const ushort* __restrict__ x1,
    const ushort* __restrict__ x2, const ushort* __restrict__ x3,
    const ushort* __restrict__ Wf,   // [kt16][jt8][lane64][8] bf16
    const float* __restrict__ jkb, float* __restrict__ out, int N){
  __shared__ ushort sB[8192];
  int tid = threadIdx.x;
  int wv = tid >> 6, lane = tid & 63;
  int quad = lane >> 4, l16 = lane & 15;
  int rowbase = blockIdx.x * 128 + wv * 32;
  int r0 = rowbase + l16;      if (r0 >= N) r0 = N - 1;
  int r1 = rowbase + 16 + l16; if (r1 >= N) r1 = N - 1;

  f32x4 acc[2][8];
  #pragma unroll
  for (int jt = 0; jt < 8; jt++){
    float b = jkb[jt * 16 + l16];
    f32x4 c = {b, b, b, b};
    acc[0][jt] = c; acc[1][jt] = c;
  }

  const ushort* srcs[4] = {emb, x1, x2, x3};
  #pragma unroll
  for (int st = 0; st < 8; st++){
    int kt0 = st * 2, kt1 = st * 2 + 1;
    const ushort* sp0 = srcs[kt0 >> 2];
    const ushort* sp1 = srcs[kt1 >> 2];
    int ao0 = (kt0 & 3) * 32 + quad * 8;
    int ao1 = (kt1 & 3) * 32 + quad * 8;
    bf16x8 aA0 = load8(sp0 + (size_t)r0 * HID + ao0);
    bf16x8 aA1 = load8(sp0 + (size_t)r1 * HID + ao0);
    bf16x8 aB0 = load8(sp1 + (size_t)r0 * HID + ao1);
    bf16x8 aB1 = load8(sp1 + (size_t)r1 * HID + ao1);
    __syncthreads();
    const ushort* src = Wf + st * 8192;
    #pragma unroll
    for (int i = 0; i < 4; i++){
      int c = i * 256 + tid;
      *(bf16x8*)(sB + c * 8) = load8(src + c * 8);
    }
    __syncthreads();
    #pragma unroll
    for (int jt = 0; jt < 8; jt++){
      bf16x8 b0 = load8(sB + (jt * 64 + lane) * 8);
      bf16x8 b1 = load8(sB + ((8 + jt) * 64 + lane) * 8);
      acc[0][jt] = __builtin_amdgcn_mfma_f32_16x16x32_bf16(aA0, b0, acc[0][jt], 0, 0, 0);
      acc[1][jt] = __builtin_amdgcn_mfma_f32_16x16x32_bf16(aA1, b0, acc[1][jt], 0, 0, 0);
      acc[0][jt] = __builtin_amdgcn_mfma_f32_16x16x32_bf16(aB0, b1, acc[0][jt], 0, 0, 0);
      acc[1][jt] = __builtin_amdgcn_mfma_f32_16x16x32_bf16(aB1, b1, acc[1][jt], 0, 0, 0);
    }
  }

  #pragma unroll
  for (int rt = 0; rt < 2; rt++){
    #pragma unroll
    for (int jt = 0; jt < 8; jt++){
      #pragma unroll
      for (int r = 0; r < 4; r++){
        int row = rowbase + rt * 16 + quad * 4 + r;
        if (row < N)
          out[(size_t)row * HID + jt * 16 + l16] = acc[rt][jt][r];
      }
    }
  }
}

extern "C" void kernel_launch(void* const* d_in, const int* in_sizes, int n_in,
                              void* d_out, int out_size, void* d_ws, size_t ws_size,
                              hipStream_t stream){
  const float* emb   = (const float*)d_in[0];
  const float* Wl    = (const float*)d_in[1];
  const float* bl    = (const float*)d_in[2];
  const float* Wr    = (const float*)d_in[3];
  const float* gamma = (const float*)d_in[4];
  const float* beta  = (const float*)d_in[5];
  const float* jkW   = (const float*)d_in[6];
  const float* jkb   = (const float*)d_in[7];
  const int*   eidx  = (const int*)d_in[8];
  int N = in_sizes[0] / HID;
  int E = in_sizes[8] / 2;
  const int* src = eidx;
  const int* dst = eidx + E;
  float* out = (float*)d_out;

  int NB = (N + 127) >> BSHIFT;        // coarse buckets of 128 nodes
  int es = (E + NBLK - 1) / NBLK;      // edges per slice block

  // workspace carve (256B aligned)
  char* w = (char*)d_ws;
  auto carve = [&](size_t bytes) -> char* {
    char* p = w; w += (bytes + 255) & ~(size_t)255; return p;
  };
  int Npad = ((N + 127) / 128) * 128;
  int* rowcnt   = (int*)carve((size_t)NBLK * NB * 4);
  int* bbase    = (int*)carve((size_t)(NB + 1) * 4);
  uint* binned  = (uint*)carve((size_t)E * 4);
  int* cnt      = (int*)carve((size_t)N * 4);
  int* offs     = (int*)carve((size_t)N * 4);
  int* csr      = (int*)carve((size_t)E * 4);
  ushort* Wfrag = (ushort*)carve((size_t)3 * 32768 * 2);
  ushort* jkWf  = (ushort*)carve((size_t)65536 * 2);
  ushort* embbf = (ushort*)carve((size_t)Npad * HID * 2);
  ushort* agg   = (ushort*)carve((size_t)Npad * HID * 2);
  ushort* x1    = (ushort*)carve((size_t)Npad * HID * 2);
  ushort* x2    = (ushort*)carve((size_t)Npad * HID * 2);
  ushort* x3    = (ushort*)carve((size_t)Npad * HID * 2);

  // weight transforms + emb cast
  int nEmb = N * HID;
  k_cvtw<<<(3 * 32768 + 255) / 256, 256, 0, stream>>>(Wl, Wr, Wfrag, 3 * 32768);
  k_cvtjk<<<65536 / 256, 256, 0, stream>>>(jkW, jkWf);
  k_cvt<<<(nEmb + 255) / 256, 256, 0, stream>>>(emb, embbf, nEmb);

  // deterministic two-level CSR build
  k_count<<<NBLK, 1024, 0, stream>>>(dst, rowcnt, E, NB, es);
  k_colscan<<<1, 1024, 0, stream>>>(rowcnt, bbase, NB, NBLK);
  k_place<<<NBLK, 1024, 0, stream>>>(src, dst, rowcnt, binned, E, NB, es);
  k_bpass<<<NB, 256, 0, stream>>>(binned, bbase, csr, offs, cnt, N);

  int aggBlocks = (N + 3) / 4;
  int gemmBlocks = (N + 127) / 128;

  // layer 0 (no residual)
  k_aggregate<<<aggBlocks, 256, 0, stream>>>(embbf, csr, offs, cnt, agg, N);
  k_layer<0><<<gemmBlocks, 256, 0, stream>>>(agg, embbf, Wfrag, bl, gamma, beta, x1, N);
  // layer 1
  k_aggregate<<<aggBlocks, 256, 0, stream>>>(x1, csr, offs, cnt, agg, N);
  k_layer<1><<<gemmBlocks, 256, 0, stream>>>(agg, x1, Wfrag + 32768, bl + HID,
                                             gamma + HID, beta + HID, x2, N);
  // layer 2
  k_aggregate<<<aggBlocks, 256, 0, stream>>>(x2, csr, offs, cnt, agg, N);
  k_layer<1><<<gemmBlocks, 256, 0, stream>>>(agg, x2, Wfrag + 2 * 32768, bl + 2 * HID,
                                             gamma + 2 * HID, beta + 2 * HID, x3, N);
  // jumping knowledge projection
  k_jk<<<gemmBlocks, 256, 0, stream>>>(embbf, x1, x2, x3, jkWf, jkb, out, N);
}